// Round 4
// baseline (497.385 us; speedup 1.0000x reference)
//
#include <hip/hip_runtime.h>
#include <stdint.h>
#include <math.h>

#define IN_DIM 128
#define H_HEADS 8
#define HD 16

typedef __attribute__((ext_vector_type(8))) short bf16x8;
typedef __attribute__((ext_vector_type(4))) float f32x4;

__device__ __forceinline__ unsigned short f2bf_rne(float f) {
    unsigned int u = __float_as_uint(f);
    unsigned int r = (u + 0x7fffu + ((u >> 16) & 1u)) >> 16;
    return (unsigned short)r;
}
__device__ __forceinline__ float bf2f(unsigned short h) {
    return __uint_as_float(((unsigned int)h) << 16);
}

__device__ __forceinline__ void split_f8(const float4 f0, const float4 f1,
                                         bf16x8& h8, bf16x8& l8) {
    float ff[8] = {f0.x, f0.y, f0.z, f0.w, f1.x, f1.y, f1.z, f1.w};
    union { bf16x8 v; unsigned short u[8]; } H, L;
#pragma unroll
    for (int j = 0; j < 8; ++j) {
        H.u[j] = f2bf_rne(ff[j]);
        L.u[j] = f2bf_rne(ff[j] - bf2f(H.u[j]));
    }
    h8 = H.v; l8 = L.v;
}

// ---------- prep (5 blocks): transpose + hi/lo split of W, biases ----------
// ---------- + count (remaining blocks): dst-degree histogram ----------
__global__ __launch_bounds__(256)
void prep_count_kernel(const float* __restrict__ Wq, const float* __restrict__ Wk,
                       const float* __restrict__ Wv, const float* __restrict__ Wsk,
                       const float* __restrict__ Wo,
                       const float* __restrict__ bq, const float* __restrict__ bk,
                       const float* __restrict__ bv, const float* __restrict__ bsk,
                       unsigned short* __restrict__ WtH, unsigned short* __restrict__ WtL,
                       float* __restrict__ bias_cat,
                       const int* __restrict__ ei, int* __restrict__ deg, int E)
{
    const int b = blockIdx.x;
    const int t = threadIdx.x;
    if (b >= 5) {
        int e = (b - 5) * 256 + t;
        if (e < E) atomicAdd(&deg[ei[E + e]], 1);   // dst row
        return;
    }
    const int p = b;
    const float* src = (p == 0) ? Wq : (p == 1) ? Wk : (p == 2) ? Wv : (p == 3) ? Wsk : Wo;
    unsigned short* dh = WtH + (size_t)p * 16384;
    unsigned short* dl = WtL + (size_t)p * 16384;
#pragma unroll
    for (int j = 0; j < 64; ++j) {
        int o = t + j * 256;            // o = c*128 + k
        int c = o >> 7, k = o & 127;
        float v;
        if (p < 4) {
            int h = c >> 4, d = c & 15;
            v = src[(size_t)h * 2048 + (size_t)k * 16 + d];
        } else {
            v = src[(size_t)k * 128 + c];
        }
        unsigned short hi = f2bf_rne(v);
        unsigned short lo = f2bf_rne(v - bf2f(hi));
        dh[o] = hi; dl[o] = lo;
    }
    if (p < 4 && t < 128) {
        const float* bb = (p == 0) ? bq : (p == 1) ? bk : (p == 2) ? bv : bsk;
        bias_cat[p * 128 + t] = bb[t];
    }
}

// ---------- proj GEMM, no LDS: direct global A-fragment loads + in-reg split ----------
// grid ceil(N/64); block 256 = 4 waves; wave w -> rows blockIdx.x*64 + w*16 .. +15.
// All 4 projections computed per wave with A-fragments loaded once.
__global__ __launch_bounds__(256)
void gemm_proj_kernel(const float* __restrict__ A,
                      const unsigned short* __restrict__ WtH_base,
                      const unsigned short* __restrict__ WtL_base,
                      const float* __restrict__ bias_cat,
                      float* __restrict__ qout, float* __restrict__ skipout,
                      unsigned short* __restrict__ kvout, int N)
{
    const int t = threadIdx.x;
    const int lane = t & 63;
    const int w = t >> 6;
    const int lr = lane & 15;
    const int lk = lane >> 4;
    const int brow0 = blockIdx.x * 64 + w * 16;
    const int arow = min(brow0 + lr, N - 1);
    const float* ap = A + (size_t)arow * 128;

    bf16x8 ah[4], al[4];
#pragma unroll
    for (int ks = 0; ks < 4; ++ks) {
        float4 f0 = *reinterpret_cast<const float4*>(ap + ks * 32 + lk * 8);
        float4 f1 = *reinterpret_cast<const float4*>(ap + ks * 32 + lk * 8 + 4);
        split_f8(f0, f1, ah[ks], al[ks]);
    }

    for (int p = 0; p < 4; ++p) {
        const unsigned short* BtH = WtH_base + (size_t)p * 16384 + (size_t)lr * 128 + lk * 8;
        const unsigned short* BtL = WtL_base + (size_t)p * 16384 + (size_t)lr * 128 + lk * 8;
        f32x4 acc[8];
#pragma unroll
        for (int ni = 0; ni < 8; ++ni) acc[ni] = (f32x4){0.f, 0.f, 0.f, 0.f};
#pragma unroll
        for (int ks = 0; ks < 4; ++ks) {
            bf16x8 bh[8], bl[8];
#pragma unroll
            for (int ni = 0; ni < 8; ++ni) {
                bh[ni] = *reinterpret_cast<const bf16x8*>(BtH + ni * 2048 + ks * 32);
                bl[ni] = *reinterpret_cast<const bf16x8*>(BtL + ni * 2048 + ks * 32);
            }
#pragma unroll
            for (int ni = 0; ni < 8; ++ni) {
                acc[ni] = __builtin_amdgcn_mfma_f32_16x16x32_bf16(ah[ks], bh[ni], acc[ni], 0, 0, 0);
                acc[ni] = __builtin_amdgcn_mfma_f32_16x16x32_bf16(ah[ks], bl[ni], acc[ni], 0, 0, 0);
                acc[ni] = __builtin_amdgcn_mfma_f32_16x16x32_bf16(al[ks], bh[ni], acc[ni], 0, 0, 0);
            }
        }
        const float* bias = bias_cat + p * 128;
        if (p == 0 || p == 3) {
            float* outp = (p == 0) ? qout : skipout;
#pragma unroll
            for (int ni = 0; ni < 8; ++ni) {
                int col = ni * 16 + lr;
                float bc = bias[col];
#pragma unroll
                for (int r = 0; r < 4; ++r) {
                    int gr = brow0 + lk * 4 + r;
                    if (gr < N) outp[(size_t)gr * 128 + col] = acc[ni][r] + bc;
                }
            }
        } else {
            const int slot = (p == 1) ? 0 : 2;   // k -> shorts 0,1 ; v -> shorts 2,3
#pragma unroll
            for (int ni = 0; ni < 8; ++ni) {
                int col = ni * 16 + lr;
                float bc = bias[col];
                int sidx = 4 * (col >> 1) + (col & 1) + slot;
#pragma unroll
                for (int r = 0; r < 4; ++r) {
                    int gr = brow0 + lk * 4 + r;
                    if (gr < N) kvout[(size_t)gr * 256 + sidx] = f2bf_rne(acc[ni][r] + bc);
                }
            }
        }
    }
}

// ---------- out GEMM + residual + fused LayerNorm, no LDS ----------
__global__ __launch_bounds__(256)
void gemm_out_ln_kernel(const float* __restrict__ A,
                        const unsigned short* __restrict__ BtH_t,
                        const unsigned short* __restrict__ BtL_t,
                        const float* __restrict__ bo,
                        const float* __restrict__ res,
                        const float* __restrict__ gamma,
                        const float* __restrict__ beta,
                        float* __restrict__ out, int N)
{
    const int t = threadIdx.x;
    const int lane = t & 63;
    const int w = t >> 6;
    const int lr = lane & 15;
    const int lk = lane >> 4;
    const int brow0 = blockIdx.x * 64 + w * 16;
    const int arow = min(brow0 + lr, N - 1);
    const float* ap = A + (size_t)arow * 128;

    bf16x8 ah[4], al[4];
#pragma unroll
    for (int ks = 0; ks < 4; ++ks) {
        float4 f0 = *reinterpret_cast<const float4*>(ap + ks * 32 + lk * 8);
        float4 f1 = *reinterpret_cast<const float4*>(ap + ks * 32 + lk * 8 + 4);
        split_f8(f0, f1, ah[ks], al[ks]);
    }

    const unsigned short* BtH = BtH_t + (size_t)lr * 128 + lk * 8;
    const unsigned short* BtL = BtL_t + (size_t)lr * 128 + lk * 8;
    f32x4 acc[8];
#pragma unroll
    for (int ni = 0; ni < 8; ++ni) acc[ni] = (f32x4){0.f, 0.f, 0.f, 0.f};
#pragma unroll
    for (int ks = 0; ks < 4; ++ks) {
        bf16x8 bh[8], bl[8];
#pragma unroll
        for (int ni = 0; ni < 8; ++ni) {
            bh[ni] = *reinterpret_cast<const bf16x8*>(BtH + ni * 2048 + ks * 32);
            bl[ni] = *reinterpret_cast<const bf16x8*>(BtL + ni * 2048 + ks * 32);
        }
#pragma unroll
        for (int ni = 0; ni < 8; ++ni) {
            acc[ni] = __builtin_amdgcn_mfma_f32_16x16x32_bf16(ah[ks], bh[ni], acc[ni], 0, 0, 0);
            acc[ni] = __builtin_amdgcn_mfma_f32_16x16x32_bf16(ah[ks], bl[ni], acc[ni], 0, 0, 0);
            acc[ni] = __builtin_amdgcn_mfma_f32_16x16x32_bf16(al[ks], bh[ni], acc[ni], 0, 0, 0);
        }
    }

    // epilogue: val = acc + bo + res; per-row LN via 16-lane shfl; write out
#pragma unroll
    for (int ni = 0; ni < 8; ++ni) {
        int col = ni * 16 + lr;
        float bc = bo[col];
#pragma unroll
        for (int r = 0; r < 4; ++r) {
            int gr = brow0 + lk * 4 + r;
            float rv = (gr < N) ? res[(size_t)gr * 128 + col] : 0.f;
            acc[ni][r] += bc + rv;
        }
    }
#pragma unroll
    for (int r = 0; r < 4; ++r) {
        float s = 0.f, sq = 0.f;
#pragma unroll
        for (int ni = 0; ni < 8; ++ni) { float v = acc[ni][r]; s += v; sq += v * v; }
#pragma unroll
        for (int mk = 1; mk < 16; mk <<= 1) {
            s  += __shfl_xor(s, mk);
            sq += __shfl_xor(sq, mk);
        }
        float mean = s * (1.0f / 128.0f);
        float var  = sq * (1.0f / 128.0f) - mean * mean;
        float inv  = rsqrtf(var + 1e-5f);
        int gr = brow0 + lk * 4 + r;
        if (gr < N) {
#pragma unroll
            for (int ni = 0; ni < 8; ++ni) {
                int col = ni * 16 + lr;
                out[(size_t)gr * 128 + col] =
                    (acc[ni][r] - mean) * inv * gamma[col] + beta[col];
            }
        }
    }
}

// ---------------- exclusive scan (single block, shfl-based) ----------------
__global__ __launch_bounds__(1024)
void scan_kernel(const int* __restrict__ deg, int* __restrict__ offs,
                 int* __restrict__ cursor, int N)
{
    __shared__ int wsum[16];
    __shared__ int chunk_total_s;
    const int t = threadIdx.x;
    const int lane = t & 63, wid = t >> 6;
    int running = 0;
    for (int base = 0; base < N; base += 4096) {
        int v[4];
        int idx = base + t * 4;
#pragma unroll
        for (int j = 0; j < 4; ++j) { int i = idx + j; v[j] = (i < N) ? deg[i] : 0; }
        int ls = v[0] + v[1] + v[2] + v[3];
        int inc = ls;
#pragma unroll
        for (int off = 1; off < 64; off <<= 1) {
            int y = __shfl_up(inc, off);
            if (lane >= off) inc += y;
        }
        if (lane == 63) wsum[wid] = inc;
        __syncthreads();
        if (t < 16) {
            int winc = wsum[t];
            for (int off = 1; off < 16; off <<= 1) {
                int y = __shfl_up(winc, off);
                if (t >= off) winc += y;
            }
            wsum[t] = winc;
            if (t == 15) chunk_total_s = winc;
        }
        __syncthreads();
        int wexcl = (wid == 0) ? 0 : wsum[wid - 1];
        int texcl = running + wexcl + (inc - ls);
        int pre = 0;
#pragma unroll
        for (int j = 0; j < 4; ++j) {
            int i = idx + j;
            if (i < N) { offs[i] = texcl + pre; cursor[i] = texcl + pre; }
            pre += v[j];
        }
        running += chunk_total_s;
        __syncthreads();
    }
    if (t == 0) offs[N] = running;
}

// ---------------- scatter edges into CSR (packed int2 {src, ea}) ----------------
__global__ void scatter_kernel(const int* __restrict__ ei, const float* __restrict__ ea,
                               int* __restrict__ cursor, int2* __restrict__ csr, int E)
{
    int e = blockIdx.x * 256 + threadIdx.x;
    if (e < E) {
        int s = ei[e], d = ei[E + e];
        int pos = atomicAdd(&cursor[d], 1);
        csr[pos] = make_int2(s, __float_as_int(ea[e]));
    }
}

// ---------------- per-node online-softmax attention + aggregation ----------------
// wave per node: 64 lanes = 8 heads x 8 lanes, 2 dims/lane. Dual-state (even/odd
// edges) breaks the serial softmax chain; single-exp update; deep prefetch.
#define GATHER(ec) (*reinterpret_cast<const ushort4*>(kvb + (size_t)(ec).x * 256 + 4 * lane))
#define PROCESS(ec, g, m, s, a0, a1) do { \
    float eav_ = __int_as_float((ec).y); \
    float ew0_ = eav_ * we2.x, ew1_ = eav_ * we2.y; \
    float dot_ = q2.x * (bf2f((g).x) + ew0_) + q2.y * (bf2f((g).y) + ew1_); \
    dot_ += __shfl_xor(dot_, 1); \
    dot_ += __shfl_xor(dot_, 2); \
    dot_ += __shfl_xor(dot_, 4); \
    float alpha_ = dot_ * 0.25f; \
    float d_ = alpha_ - (m); \
    float e_ = __expf(-fabsf(d_)); \
    bool up_ = d_ > 0.f; \
    float pv_ = up_ ? 1.f : e_; \
    float sc_ = up_ ? e_ : 1.f; \
    (m) = up_ ? alpha_ : (m); \
    (s) = (s) * sc_ + pv_; \
    (a0) = (a0) * sc_ + pv_ * (bf2f((g).z) + ew0_); \
    (a1) = (a1) * sc_ + pv_ * (bf2f((g).w) + ew1_); \
} while (0)

__global__ __launch_bounds__(256)
void agg_kernel(const float* __restrict__ qb, const float* __restrict__ sb,
                const unsigned short* __restrict__ kvb,
                const int* __restrict__ offs, const int2* __restrict__ csr,
                const float* __restrict__ We, float* __restrict__ heads_cat, int N)
{
    const int lane = threadIdx.x & 63;
    const int node = blockIdx.x * 4 + (threadIdx.x >> 6);
    if (node >= N) return;

    const float2 q2  = *reinterpret_cast<const float2*>(qb + (size_t)node * 128 + 2 * lane);
    const float2 we2 = *reinterpret_cast<const float2*>(We + 2 * lane);

    const int e0 = offs[node];
    const int cnt = offs[node + 1] - e0;

    float mA = -__builtin_huge_valf(), sA = 0.f, a0A = 0.f, a1A = 0.f;
    float mB = -__builtin_huge_valf(), sB = 0.f, a0B = 0.f, a1B = 0.f;

    int2 c0, c1, c2, c3, c4, c5;
    ushort4 g0, g1, g2, g3;
    if (cnt > 0) c0 = csr[e0];
    if (cnt > 1) c1 = csr[e0 + 1];
    if (cnt > 2) c2 = csr[e0 + 2];
    if (cnt > 3) c3 = csr[e0 + 3];
    if (cnt > 4) c4 = csr[e0 + 4];
    if (cnt > 5) c5 = csr[e0 + 5];
    if (cnt > 0) g0 = GATHER(c0);
    if (cnt > 1) g1 = GATHER(c1);
    if (cnt > 2) g2 = GATHER(c2);
    if (cnt > 3) g3 = GATHER(c3);

    int i = 0;
    for (; i + 1 < cnt; i += 2) {
        PROCESS(c0, g0, mA, sA, a0A, a1A);
        PROCESS(c1, g1, mB, sB, a0B, a1B);
        c0 = c2; c1 = c3; g0 = g2; g1 = g3;
        c2 = c4; c3 = c5;
        if (i + 6 < cnt) c4 = csr[e0 + i + 6];
        if (i + 7 < cnt) c5 = csr[e0 + i + 7];
        if (i + 4 < cnt) g2 = GATHER(c2);
        if (i + 5 < cnt) g3 = GATHER(c3);
    }
    if (i < cnt) PROCESS(c0, g0, mA, sA, a0A, a1A);

    float s, a0, a1;
    {
        float nm = fmaxf(mA, mB);
        float eA = (cnt > 0) ? __expf(mA - nm) : 0.f;
        float eB = (cnt > 1) ? __expf(mB - nm) : 0.f;
        s  = sA * eA + sB * eB;
        a0 = a0A * eA + a0B * eB;
        a1 = a1A * eA + a1B * eB;
    }

    float inv = 1.0f / fmaxf(s, 1e-16f);
    const float2 sk = *reinterpret_cast<const float2*>(sb + (size_t)node * 128 + 2 * lane);
    float2 o;
    o.x = a0 * inv + sk.x;
    o.y = a1 * inv + sk.y;
    *reinterpret_cast<float2*>(heads_cat + (size_t)node * 128 + 2 * lane) = o;
}

extern "C" void kernel_launch(void* const* d_in, const int* in_sizes, int n_in,
                              void* d_out, int out_size, void* d_ws, size_t ws_size,
                              hipStream_t stream)
{
    const float* x    = (const float*)d_in[0];
    const int*   ei   = (const int*)d_in[1];
    const float* ea   = (const float*)d_in[2];
    const float* Wq   = (const float*)d_in[3];
    const float* bq   = (const float*)d_in[4];
    const float* Wk   = (const float*)d_in[5];
    const float* bk   = (const float*)d_in[6];
    const float* Wv   = (const float*)d_in[7];
    const float* bv   = (const float*)d_in[8];
    const float* We   = (const float*)d_in[9];
    const float* Wsk  = (const float*)d_in[10];
    const float* bsk  = (const float*)d_in[11];
    const float* Wo   = (const float*)d_in[12];
    const float* bo   = (const float*)d_in[13];
    const float* gamma= (const float*)d_in[14];
    const float* beta = (const float*)d_in[15];
    const int N = in_sizes[0] / 128;
    const int E = in_sizes[1] / 2;
    float* out = (float*)d_out;

    char* w = (char*)d_ws;
    float* qarr      = (float*)w; w += (size_t)N * 128 * sizeof(float);
    float* skiparr   = (float*)w; w += (size_t)N * 128 * sizeof(float);
    unsigned short* kv = (unsigned short*)w; w += (size_t)N * 256 * sizeof(unsigned short);
    float* heads_cat = (float*)w; w += (size_t)N * 128 * sizeof(float);
    int*   deg       = (int*)w;   w += ((size_t)N + 16) * sizeof(int);
    int*   offs      = (int*)w;   w += ((size_t)N + 16) * sizeof(int);
    int*   cursor    = (int*)w;   w += ((size_t)N + 16) * sizeof(int);
    int2*  csr       = (int2*)w;  w += (size_t)E * sizeof(int2);
    unsigned short* WtH = (unsigned short*)w; w += (size_t)5 * 16384 * sizeof(unsigned short);
    unsigned short* WtL = (unsigned short*)w; w += (size_t)5 * 16384 * sizeof(unsigned short);
    float* bias_cat  = (float*)w; w += 4 * 128 * sizeof(float);

    hipMemsetAsync(deg, 0, (size_t)N * sizeof(int), stream);

    const int cntBlocks = (E + 255) / 256;
    prep_count_kernel<<<5 + cntBlocks, 256, 0, stream>>>(Wq, Wk, Wv, Wsk, Wo, bq, bk, bv, bsk,
                                                         WtH, WtL, bias_cat, ei, deg, E);

    const int gx64 = (N + 63) / 64;
    gemm_proj_kernel<<<gx64, 256, 0, stream>>>(x, WtH, WtL, bias_cat, qarr, skiparr, kv, N);

    scan_kernel<<<1, 1024, 0, stream>>>(deg, offs, cursor, N);
    scatter_kernel<<<(E + 255) / 256, 256, 0, stream>>>(ei, ea, cursor, csr, E);
    agg_kernel<<<(N + 3) / 4, 256, 0, stream>>>(qarr, skiparr, kv, offs, csr, We, heads_cat, N);

    gemm_out_ln_kernel<<<gx64, 256, 0, stream>>>(heads_cat, WtH + (size_t)4 * 16384, WtL + (size_t)4 * 16384,
                                                 bo, x, gamma, beta, out, N);
}

// Round 5
// 376.494 us; speedup vs baseline: 1.3211x; 1.3211x over previous
//
#include <hip/hip_runtime.h>
#include <stdint.h>
#include <math.h>

#define IN_DIM 128
#define H_HEADS 8
#define HD 16

typedef __attribute__((ext_vector_type(8))) short bf16x8;
typedef __attribute__((ext_vector_type(4))) float f32x4;

__device__ __forceinline__ unsigned short f2bf_rne(float f) {
    unsigned int u = __float_as_uint(f);
    unsigned int r = (u + 0x7fffu + ((u >> 16) & 1u)) >> 16;
    return (unsigned short)r;
}
__device__ __forceinline__ float bf2f(unsigned short h) {
    return __uint_as_float(((unsigned int)h) << 16);
}

__device__ __forceinline__ void split_f8(const float4 f0, const float4 f1,
                                         bf16x8& h8, bf16x8& l8) {
    float ff[8] = {f0.x, f0.y, f0.z, f0.w, f1.x, f1.y, f1.z, f1.w};
    union { bf16x8 v; unsigned short u[8]; } H, L;
#pragma unroll
    for (int j = 0; j < 8; ++j) {
        H.u[j] = f2bf_rne(ff[j]);
        L.u[j] = f2bf_rne(ff[j] - bf2f(H.u[j]));
    }
    h8 = H.v; l8 = L.v;
}

// stage one 32KB B matrix ([c][k] 128x128 shorts) into LDS with XOR-swizzled
// 16B columns: lds[c*128 + ((kcol ^ (c&15))*8)] <- B[c*128 + kcol*8]
__device__ __forceinline__ void stage_B(const unsigned short* __restrict__ src,
                                        unsigned short* __restrict__ lds, int t)
{
#pragma unroll
    for (int j = 0; j < 8; ++j) {
        int idx16 = t + j * 256;            // 2048 16B chunks
        int c = idx16 >> 4, kcol = idx16 & 15;
        uint4 v = *reinterpret_cast<const uint4*>(src + (size_t)c * 128 + kcol * 8);
        *reinterpret_cast<uint4*>(lds + c * 128 + ((kcol ^ (c & 15)) * 8)) = v;
    }
}
// fragment read: c = output-col row of Bt, kcol16 = ks*4+lk
__device__ __forceinline__ bf16x8 read_B(const unsigned short* __restrict__ lds,
                                         int c, int kcol)
{
    return *reinterpret_cast<const bf16x8*>(lds + c * 128 + ((kcol ^ (c & 15)) * 8));
}

// ---------- prep (5 blocks): transpose + hi/lo split of W, biases ----------
// ---------- + count (remaining blocks): dst-degree histogram ----------
__global__ __launch_bounds__(256)
void prep_count_kernel(const float* __restrict__ Wq, const float* __restrict__ Wk,
                       const float* __restrict__ Wv, const float* __restrict__ Wsk,
                       const float* __restrict__ Wo,
                       const float* __restrict__ bq, const float* __restrict__ bk,
                       const float* __restrict__ bv, const float* __restrict__ bsk,
                       unsigned short* __restrict__ WtH, unsigned short* __restrict__ WtL,
                       float* __restrict__ bias_cat,
                       const int* __restrict__ ei, int* __restrict__ deg, int E)
{
    const int b = blockIdx.x;
    const int t = threadIdx.x;
    if (b >= 5) {
        int e = (b - 5) * 256 + t;
        if (e < E) atomicAdd(&deg[ei[E + e]], 1);   // dst row
        return;
    }
    const int p = b;
    const float* src = (p == 0) ? Wq : (p == 1) ? Wk : (p == 2) ? Wv : (p == 3) ? Wsk : Wo;
    unsigned short* dh = WtH + (size_t)p * 16384;
    unsigned short* dl = WtL + (size_t)p * 16384;
#pragma unroll
    for (int j = 0; j < 64; ++j) {
        int o = t + j * 256;            // o = c*128 + k
        int c = o >> 7, k = o & 127;
        float v;
        if (p < 4) {
            int h = c >> 4, d = c & 15;
            v = src[(size_t)h * 2048 + (size_t)k * 16 + d];
        } else {
            v = src[(size_t)k * 128 + c];
        }
        unsigned short hi = f2bf_rne(v);
        unsigned short lo = f2bf_rne(v - bf2f(hi));
        dh[o] = hi; dl[o] = lo;
    }
    if (p < 4 && t < 128) {
        const float* bb = (p == 0) ? bq : (p == 1) ? bk : (p == 2) ? bv : bsk;
        bias_cat[p * 128 + t] = bb[t];
    }
}

// ---------- proj GEMM: LDS-staged B (two-pass hi/lo), A direct from global ----------
// grid (ceil(N/64), 4); block 256 = 4 waves; wave w -> 16 rows x 128 cols of proj p.
__global__ __launch_bounds__(256)
void gemm_proj_kernel(const float* __restrict__ A,
                      const unsigned short* __restrict__ WtH_base,
                      const unsigned short* __restrict__ WtL_base,
                      const float* __restrict__ bias_cat,
                      float* __restrict__ qout, float* __restrict__ skipout,
                      unsigned short* __restrict__ kvout, int N)
{
    __shared__ unsigned short Bs[16384];    // 32KB, one half (hi or lo) at a time
    const int t = threadIdx.x;
    const int lane = t & 63;
    const int w = t >> 6;
    const int lr = lane & 15;
    const int lk = lane >> 4;
    const int p = blockIdx.y;               // 0=q 1=k 2=v 3=skip
    const int brow0 = blockIdx.x * 64 + w * 16;
    const int arow = min(brow0 + lr, N - 1);
    const float* ap = A + (size_t)arow * 128;

    bf16x8 ah[4], al[4];
#pragma unroll
    for (int ks = 0; ks < 4; ++ks) {
        float4 f0 = *reinterpret_cast<const float4*>(ap + ks * 32 + lk * 8);
        float4 f1 = *reinterpret_cast<const float4*>(ap + ks * 32 + lk * 8 + 4);
        split_f8(f0, f1, ah[ks], al[ks]);
    }

    f32x4 acc[8];
#pragma unroll
    for (int ni = 0; ni < 8; ++ni) acc[ni] = (f32x4){0.f, 0.f, 0.f, 0.f};

    // pass 1: B-hi -> ah*bh + al*bh
    stage_B(WtH_base + (size_t)p * 16384, Bs, t);
    __syncthreads();
#pragma unroll
    for (int ks = 0; ks < 4; ++ks)
#pragma unroll
        for (int ni = 0; ni < 8; ++ni) {
            bf16x8 bh = read_B(Bs, ni * 16 + lr, ks * 4 + lk);
            acc[ni] = __builtin_amdgcn_mfma_f32_16x16x32_bf16(ah[ks], bh, acc[ni], 0, 0, 0);
            acc[ni] = __builtin_amdgcn_mfma_f32_16x16x32_bf16(al[ks], bh, acc[ni], 0, 0, 0);
        }
    __syncthreads();
    // pass 2: B-lo -> ah*bl
    stage_B(WtL_base + (size_t)p * 16384, Bs, t);
    __syncthreads();
#pragma unroll
    for (int ks = 0; ks < 4; ++ks)
#pragma unroll
        for (int ni = 0; ni < 8; ++ni) {
            bf16x8 bl = read_B(Bs, ni * 16 + lr, ks * 4 + lk);
            acc[ni] = __builtin_amdgcn_mfma_f32_16x16x32_bf16(ah[ks], bl, acc[ni], 0, 0, 0);
        }

    const float* bias = bias_cat + p * 128;
    if (p == 0 || p == 3) {
        float* outp = (p == 0) ? qout : skipout;
#pragma unroll
        for (int ni = 0; ni < 8; ++ni) {
            int col = ni * 16 + lr;
            float bc = bias[col];
#pragma unroll
            for (int r = 0; r < 4; ++r) {
                int gr = brow0 + lk * 4 + r;
                if (gr < N) outp[(size_t)gr * 128 + col] = acc[ni][r] + bc;
            }
        }
    } else {
        // packed kv: uint idx = gr*128 + 2*(col>>1) + slot ; pair via shfl_xor(1)
        unsigned int* kvu = (unsigned int*)kvout;
        const int slot = (p == 1) ? 0 : 1;
#pragma unroll
        for (int ni = 0; ni < 8; ++ni) {
            int col = ni * 16 + lr;
            float bc = bias[col];
#pragma unroll
            for (int r = 0; r < 4; ++r) {
                unsigned int s = f2bf_rne(acc[ni][r] + bc);
                unsigned int o = __shfl_xor((int)s, 1);
                int gr = brow0 + lk * 4 + r;
                if (((lr & 1) == 0) && gr < N)
                    kvu[(size_t)gr * 128 + 2 * (col >> 1) + slot] = s | (o << 16);
            }
        }
    }
}

// ---------- out GEMM + residual + fused LayerNorm ----------
// grid ceil(N/32); block 256 = 4 waves; wave w: rows (w>>1)*16, cols (w&1)*64.
__global__ __launch_bounds__(256)
void gemm_out_ln_kernel(const float* __restrict__ A,
                        const unsigned short* __restrict__ BtH_t,
                        const unsigned short* __restrict__ BtL_t,
                        const float* __restrict__ bo,
                        const float* __restrict__ res,
                        const float* __restrict__ gamma,
                        const float* __restrict__ beta,
                        float* __restrict__ out, int N)
{
    __shared__ unsigned short Bs[16384];    // 32KB
    __shared__ float lnS[2][32], lnSq[2][32];
    const int t = threadIdx.x;
    const int lane = t & 63;
    const int w = t >> 6;
    const int lr = lane & 15;
    const int lk = lane >> 4;
    const int ch = w & 1;                   // col half
    const int rg = w >> 1;                  // row group
    const int brow0 = blockIdx.x * 32 + rg * 16;
    const int arow = min(brow0 + lr, N - 1);
    const float* ap = A + (size_t)arow * 128;

    bf16x8 ah[4], al[4];
#pragma unroll
    for (int ks = 0; ks < 4; ++ks) {
        float4 f0 = *reinterpret_cast<const float4*>(ap + ks * 32 + lk * 8);
        float4 f1 = *reinterpret_cast<const float4*>(ap + ks * 32 + lk * 8 + 4);
        split_f8(f0, f1, ah[ks], al[ks]);
    }

    f32x4 acc[4];
#pragma unroll
    for (int ni = 0; ni < 4; ++ni) acc[ni] = (f32x4){0.f, 0.f, 0.f, 0.f};

    stage_B(BtH_t, Bs, t);
    __syncthreads();
#pragma unroll
    for (int ks = 0; ks < 4; ++ks)
#pragma unroll
        for (int ni = 0; ni < 4; ++ni) {
            bf16x8 bh = read_B(Bs, ch * 64 + ni * 16 + lr, ks * 4 + lk);
            acc[ni] = __builtin_amdgcn_mfma_f32_16x16x32_bf16(ah[ks], bh, acc[ni], 0, 0, 0);
            acc[ni] = __builtin_amdgcn_mfma_f32_16x16x32_bf16(al[ks], bh, acc[ni], 0, 0, 0);
        }
    __syncthreads();
    stage_B(BtL_t, Bs, t);
    __syncthreads();
#pragma unroll
    for (int ks = 0; ks < 4; ++ks)
#pragma unroll
        for (int ni = 0; ni < 4; ++ni) {
            bf16x8 bl = read_B(Bs, ch * 64 + ni * 16 + lr, ks * 4 + lk);
            acc[ni] = __builtin_amdgcn_mfma_f32_16x16x32_bf16(ah[ks], bl, acc[ni], 0, 0, 0);
        }

    // add bias + residual
#pragma unroll
    for (int ni = 0; ni < 4; ++ni) {
        int col = ch * 64 + ni * 16 + lr;
        float bc = bo[col];
#pragma unroll
        for (int r = 0; r < 4; ++r) {
            int gr = brow0 + lk * 4 + r;
            float rv = (gr < N) ? res[(size_t)gr * 128 + col] : 0.f;
            acc[ni][r] += bc + rv;
        }
    }
    // per-row partial sums over this wave's 64 cols (reduce across lr lanes)
    float ps[4], pq[4];
#pragma unroll
    for (int r = 0; r < 4; ++r) {
        float s = 0.f, sq = 0.f;
#pragma unroll
        for (int ni = 0; ni < 4; ++ni) { float v = acc[ni][r]; s += v; sq += v * v; }
#pragma unroll
        for (int mk = 1; mk < 16; mk <<= 1) {
            s  += __shfl_xor(s, mk);
            sq += __shfl_xor(sq, mk);
        }
        ps[r] = s; pq[r] = sq;
    }
    if (lr == 0) {
#pragma unroll
        for (int r = 0; r < 4; ++r) {
            lnS [ch][rg * 16 + lk * 4 + r] = ps[r];
            lnSq[ch][rg * 16 + lk * 4 + r] = pq[r];
        }
    }
    __syncthreads();
#pragma unroll
    for (int r = 0; r < 4; ++r) {
        int rib = rg * 16 + lk * 4 + r;
        float s  = lnS [0][rib] + lnS [1][rib];
        float sq = lnSq[0][rib] + lnSq[1][rib];
        float mean = s * (1.0f / 128.0f);
        float var  = sq * (1.0f / 128.0f) - mean * mean;
        float inv  = rsqrtf(var + 1e-5f);
        int gr = brow0 + lk * 4 + r;
        if (gr < N) {
#pragma unroll
            for (int ni = 0; ni < 4; ++ni) {
                int col = ch * 64 + ni * 16 + lr;
                out[(size_t)gr * 128 + col] =
                    (acc[ni][r] - mean) * inv * gamma[col] + beta[col];
            }
        }
    }
}

// ---------------- exclusive scan (single block, shfl-based) ----------------
__global__ __launch_bounds__(1024)
void scan_kernel(const int* __restrict__ deg, int* __restrict__ offs,
                 int* __restrict__ cursor, int N)
{
    __shared__ int wsum[16];
    __shared__ int chunk_total_s;
    const int t = threadIdx.x;
    const int lane = t & 63, wid = t >> 6;
    int running = 0;
    for (int base = 0; base < N; base += 4096) {
        int v[4];
        int idx = base + t * 4;
#pragma unroll
        for (int j = 0; j < 4; ++j) { int i = idx + j; v[j] = (i < N) ? deg[i] : 0; }
        int ls = v[0] + v[1] + v[2] + v[3];
        int inc = ls;
#pragma unroll
        for (int off = 1; off < 64; off <<= 1) {
            int y = __shfl_up(inc, off);
            if (lane >= off) inc += y;
        }
        if (lane == 63) wsum[wid] = inc;
        __syncthreads();
        if (t < 16) {
            int winc = wsum[t];
            for (int off = 1; off < 16; off <<= 1) {
                int y = __shfl_up(winc, off);
                if (t >= off) winc += y;
            }
            wsum[t] = winc;
            if (t == 15) chunk_total_s = winc;
        }
        __syncthreads();
        int wexcl = (wid == 0) ? 0 : wsum[wid - 1];
        int texcl = running + wexcl + (inc - ls);
        int pre = 0;
#pragma unroll
        for (int j = 0; j < 4; ++j) {
            int i = idx + j;
            if (i < N) { offs[i] = texcl + pre; cursor[i] = texcl + pre; }
            pre += v[j];
        }
        running += chunk_total_s;
        __syncthreads();
    }
    if (t == 0) offs[N] = running;
}

// ---------------- scatter edges into CSR (packed int2 {src, ea}) ----------------
__global__ void scatter_kernel(const int* __restrict__ ei, const float* __restrict__ ea,
                               int* __restrict__ cursor, int2* __restrict__ csr, int E)
{
    int e = blockIdx.x * 256 + threadIdx.x;
    if (e < E) {
        int s = ei[e], d = ei[E + e];
        int pos = atomicAdd(&cursor[d], 1);
        csr[pos] = make_int2(s, __float_as_int(ea[e]));
    }
}

// ---------------- per-node online-softmax attention + aggregation ----------------
#define GATHER(ec) (*reinterpret_cast<const ushort4*>(kvb + (size_t)(ec).x * 256 + 4 * lane))
#define PROCESS(ec, g, m, s, a0, a1) do { \
    float eav_ = __int_as_float((ec).y); \
    float ew0_ = eav_ * we2.x, ew1_ = eav_ * we2.y; \
    float dot_ = q2.x * (bf2f((g).x) + ew0_) + q2.y * (bf2f((g).y) + ew1_); \
    dot_ += __shfl_xor(dot_, 1); \
    dot_ += __shfl_xor(dot_, 2); \
    dot_ += __shfl_xor(dot_, 4); \
    float alpha_ = dot_ * 0.25f; \
    float d_ = alpha_ - (m); \
    float e_ = __expf(-fabsf(d_)); \
    bool up_ = d_ > 0.f; \
    float pv_ = up_ ? 1.f : e_; \
    float sc_ = up_ ? e_ : 1.f; \
    (m) = up_ ? alpha_ : (m); \
    (s) = (s) * sc_ + pv_; \
    (a0) = (a0) * sc_ + pv_ * (bf2f((g).z) + ew0_); \
    (a1) = (a1) * sc_ + pv_ * (bf2f((g).w) + ew1_); \
} while (0)

__global__ __launch_bounds__(256)
void agg_kernel(const float* __restrict__ qb, const float* __restrict__ sb,
                const unsigned short* __restrict__ kvb,
                const int* __restrict__ offs, const int2* __restrict__ csr,
                const float* __restrict__ We, float* __restrict__ heads_cat, int N)
{
    const int lane = threadIdx.x & 63;
    const int node = blockIdx.x * 4 + (threadIdx.x >> 6);
    if (node >= N) return;

    const float2 q2  = *reinterpret_cast<const float2*>(qb + (size_t)node * 128 + 2 * lane);
    const float2 we2 = *reinterpret_cast<const float2*>(We + 2 * lane);

    const int e0 = offs[node];
    const int cnt = offs[node + 1] - e0;

    float mA = -__builtin_huge_valf(), sA = 0.f, a0A = 0.f, a1A = 0.f;
    float mB = -__builtin_huge_valf(), sB = 0.f, a0B = 0.f, a1B = 0.f;

    int2 c0, c1, c2, c3, c4, c5;
    ushort4 g0, g1, g2, g3;
    if (cnt > 0) c0 = csr[e0];
    if (cnt > 1) c1 = csr[e0 + 1];
    if (cnt > 2) c2 = csr[e0 + 2];
    if (cnt > 3) c3 = csr[e0 + 3];
    if (cnt > 4) c4 = csr[e0 + 4];
    if (cnt > 5) c5 = csr[e0 + 5];
    if (cnt > 0) g0 = GATHER(c0);
    if (cnt > 1) g1 = GATHER(c1);
    if (cnt > 2) g2 = GATHER(c2);
    if (cnt > 3) g3 = GATHER(c3);

    int i = 0;
    for (; i + 1 < cnt; i += 2) {
        PROCESS(c0, g0, mA, sA, a0A, a1A);
        PROCESS(c1, g1, mB, sB, a0B, a1B);
        c0 = c2; c1 = c3; g0 = g2; g1 = g3;
        c2 = c4; c3 = c5;
        if (i + 6 < cnt) c4 = csr[e0 + i + 6];
        if (i + 7 < cnt) c5 = csr[e0 + i + 7];
        if (i + 4 < cnt) g2 = GATHER(c2);
        if (i + 5 < cnt) g3 = GATHER(c3);
    }
    if (i < cnt) PROCESS(c0, g0, mA, sA, a0A, a1A);

    float s, a0, a1;
    {
        float nm = fmaxf(mA, mB);
        float eA = (cnt > 0) ? __expf(mA - nm) : 0.f;
        float eB = (cnt > 1) ? __expf(mB - nm) : 0.f;
        s  = sA * eA + sB * eB;
        a0 = a0A * eA + a0B * eB;
        a1 = a1A * eA + a1B * eB;
    }

    float inv = 1.0f / fmaxf(s, 1e-16f);
    const float2 sk = *reinterpret_cast<const float2*>(sb + (size_t)node * 128 + 2 * lane);
    float2 o;
    o.x = a0 * inv + sk.x;
    o.y = a1 * inv + sk.y;
    *reinterpret_cast<float2*>(heads_cat + (size_t)node * 128 + 2 * lane) = o;
}

extern "C" void kernel_launch(void* const* d_in, const int* in_sizes, int n_in,
                              void* d_out, int out_size, void* d_ws, size_t ws_size,
                              hipStream_t stream)
{
    const float* x    = (const float*)d_in[0];
    const int*   ei   = (const int*)d_in[1];
    const float* ea   = (const float*)d_in[2];
    const float* Wq   = (const float*)d_in[3];
    const float* bq   = (const float*)d_in[4];
    const float* Wk   = (const float*)d_in[5];
    const float* bk   = (const float*)d_in[6];
    const float* Wv   = (const float*)d_in[7];
    const float* bv   = (const float*)d_in[8];
    const float* We   = (const float*)d_in[9];
    const float* Wsk  = (const float*)d_in[10];
    const float* bsk  = (const float*)d_in[11];
    const float* Wo   = (const float*)d_in[12];
    const float* bo   = (const float*)d_in[13];
    const float* gamma= (const float*)d_in[14];
    const float* beta = (const float*)d_in[15];
    const int N = in_sizes[0] / 128;
    const int E = in_sizes[1] / 2;
    float* out = (float*)d_out;

    char* w = (char*)d_ws;
    float* qarr      = (float*)w; w += (size_t)N * 128 * sizeof(float);
    float* skiparr   = (float*)w; w += (size_t)N * 128 * sizeof(float);
    unsigned short* kv = (unsigned short*)w; w += (size_t)N * 256 * sizeof(unsigned short);
    float* heads_cat = (float*)w; w += (size_t)N * 128 * sizeof(float);
    int*   deg       = (int*)w;   w += ((size_t)N + 16) * sizeof(int);
    int*   offs      = (int*)w;   w += ((size_t)N + 16) * sizeof(int);
    int*   cursor    = (int*)w;   w += ((size_t)N + 16) * sizeof(int);
    int2*  csr       = (int2*)w;  w += (size_t)E * sizeof(int2);
    unsigned short* WtH = (unsigned short*)w; w += (size_t)5 * 16384 * sizeof(unsigned short);
    unsigned short* WtL = (unsigned short*)w; w += (size_t)5 * 16384 * sizeof(unsigned short);
    float* bias_cat  = (float*)w; w += 4 * 128 * sizeof(float);

    hipMemsetAsync(deg, 0, (size_t)N * sizeof(int), stream);

    const int cntBlocks = (E + 255) / 256;
    prep_count_kernel<<<5 + cntBlocks, 256, 0, stream>>>(Wq, Wk, Wv, Wsk, Wo, bq, bk, bv, bsk,
                                                         WtH, WtL, bias_cat, ei, deg, E);

    dim3 gProj((N + 63) / 64, 4);
    gemm_proj_kernel<<<gProj, 256, 0, stream>>>(x, WtH, WtL, bias_cat, qarr, skiparr, kv, N);

    scan_kernel<<<1, 1024, 0, stream>>>(deg, offs, cursor, N);
    scatter_kernel<<<(E + 255) / 256, 256, 0, stream>>>(ei, ea, cursor, csr, E);
    agg_kernel<<<(N + 3) / 4, 256, 0, stream>>>(qarr, skiparr, kv, offs, csr, We, heads_cat, N);

    gemm_out_ln_kernel<<<(N + 31) / 32, 256, 0, stream>>>(heads_cat,
                                                          WtH + (size_t)4 * 16384,
                                                          WtL + (size_t)4 * 16384,
                                                          bo, x, gamma, beta, out, N);
}

// Round 7
// 357.030 us; speedup vs baseline: 1.3931x; 1.0545x over previous
//
#include <hip/hip_runtime.h>
#include <hip/hip_bf16.h>
#include <stdint.h>
#include <math.h>

#define IN_DIM 128
#define H_HEADS 8
#define HD 16

typedef __attribute__((ext_vector_type(8))) short bf16x8;
typedef __attribute__((ext_vector_type(4))) float f32x4;

__device__ __forceinline__ unsigned short f2bf(float f) {
    __hip_bfloat16 h = __float2bfloat16(f);     // RNE; compiler emits v_cvt_pk_bf16_f32 pairs
    return reinterpret_cast<unsigned short&>(h);
}
__device__ __forceinline__ float bf2f(unsigned short h) {
    return __uint_as_float(((unsigned int)h) << 16);
}

__device__ __forceinline__ void split_f8(const float4 f0, const float4 f1,
                                         bf16x8& h8, bf16x8& l8) {
    float ff[8] = {f0.x, f0.y, f0.z, f0.w, f1.x, f1.y, f1.z, f1.w};
    union { bf16x8 v; unsigned short u[8]; } H, L;
#pragma unroll
    for (int j = 0; j < 8; ++j) {
        H.u[j] = f2bf(ff[j]);
        L.u[j] = f2bf(ff[j] - bf2f(H.u[j]));
    }
    h8 = H.v; l8 = L.v;
}

// stage one 32KB B matrix ([c][k] 128x128 shorts) into LDS with XOR-swizzled
// 16B columns: lds[c*128 + ((kcol ^ (c&15))*8)] <- B[c*128 + kcol*8]
__device__ __forceinline__ void stage_B(const unsigned short* __restrict__ src,
                                        unsigned short* __restrict__ lds, int t)
{
#pragma unroll
    for (int j = 0; j < 8; ++j) {
        int idx16 = t + j * 256;            // 2048 16B chunks
        int c = idx16 >> 4, kcol = idx16 & 15;
        uint4 v = *reinterpret_cast<const uint4*>(src + (size_t)c * 128 + kcol * 8);
        *reinterpret_cast<uint4*>(lds + c * 128 + ((kcol ^ (c & 15)) * 8)) = v;
    }
}
__device__ __forceinline__ bf16x8 read_B(const unsigned short* __restrict__ lds,
                                         int c, int kcol)
{
    return *reinterpret_cast<const bf16x8*>(lds + c * 128 + ((kcol ^ (c & 15)) * 8));
}

// ---------- prep (5 blocks): transpose + hi/lo split of W, biases ----------
// ---------- + count (remaining blocks): dst-degree histogram ----------
__global__ __launch_bounds__(256)
void prep_count_kernel(const float* __restrict__ Wq, const float* __restrict__ Wk,
                       const float* __restrict__ Wv, const float* __restrict__ Wsk,
                       const float* __restrict__ Wo,
                       const float* __restrict__ bq, const float* __restrict__ bk,
                       const float* __restrict__ bv, const float* __restrict__ bsk,
                       unsigned short* __restrict__ WtH, unsigned short* __restrict__ WtL,
                       float* __restrict__ bias_cat,
                       const int* __restrict__ ei, int* __restrict__ deg, int E)
{
    const int b = blockIdx.x;
    const int t = threadIdx.x;
    if (b >= 5) {
        int e = (b - 5) * 256 + t;
        if (e < E) atomicAdd(&deg[ei[E + e]], 1);   // dst row
        return;
    }
    const int p = b;
    const float* src = (p == 0) ? Wq : (p == 1) ? Wk : (p == 2) ? Wv : (p == 3) ? Wsk : Wo;
    unsigned short* dh = WtH + (size_t)p * 16384;
    unsigned short* dl = WtL + (size_t)p * 16384;
#pragma unroll
    for (int j = 0; j < 64; ++j) {
        int o = t + j * 256;            // o = c*128 + k
        int c = o >> 7, k = o & 127;
        float v;
        if (p < 4) {
            int h = c >> 4, d = c & 15;
            v = src[(size_t)h * 2048 + (size_t)k * 16 + d];
        } else {
            v = src[(size_t)k * 128 + c];
        }
        unsigned short hi = f2bf(v);
        unsigned short lo = f2bf(v - bf2f(hi));
        dh[o] = hi; dl[o] = lo;
    }
    if (p < 4 && t < 128) {
        const float* bb = (p == 0) ? bq : (p == 1) ? bk : (p == 2) ? bv : bsk;
        bias_cat[p * 128 + t] = bb[t];
    }
}

// ---------- proj GEMM: LDS-staged B (two-pass hi/lo), A direct from global ----------
__global__ __launch_bounds__(256)
void gemm_proj_kernel(const float* __restrict__ A,
                      const unsigned short* __restrict__ WtH_base,
                      const unsigned short* __restrict__ WtL_base,
                      const float* __restrict__ bias_cat,
                      float* __restrict__ qout, float* __restrict__ skipout,
                      unsigned short* __restrict__ kvout, int N)
{
    __shared__ unsigned short Bs[16384];    // 32KB, one half (hi or lo) at a time
    const int t = threadIdx.x;
    const int lane = t & 63;
    const int w = t >> 6;
    const int lr = lane & 15;
    const int lk = lane >> 4;
    const int p = blockIdx.y;               // 0=q 1=k 2=v 3=skip
    const int brow0 = blockIdx.x * 64 + w * 16;
    const int arow = min(brow0 + lr, N - 1);
    const float* ap = A + (size_t)arow * 128;

    bf16x8 ah[4], al[4];
#pragma unroll
    for (int ks = 0; ks < 4; ++ks) {
        float4 f0 = *reinterpret_cast<const float4*>(ap + ks * 32 + lk * 8);
        float4 f1 = *reinterpret_cast<const float4*>(ap + ks * 32 + lk * 8 + 4);
        split_f8(f0, f1, ah[ks], al[ks]);
    }

    f32x4 acc[8];
#pragma unroll
    for (int ni = 0; ni < 8; ++ni) acc[ni] = (f32x4){0.f, 0.f, 0.f, 0.f};

    stage_B(WtH_base + (size_t)p * 16384, Bs, t);
    __syncthreads();
#pragma unroll
    for (int ks = 0; ks < 4; ++ks)
#pragma unroll
        for (int ni = 0; ni < 8; ++ni) {
            bf16x8 bh = read_B(Bs, ni * 16 + lr, ks * 4 + lk);
            acc[ni] = __builtin_amdgcn_mfma_f32_16x16x32_bf16(ah[ks], bh, acc[ni], 0, 0, 0);
            acc[ni] = __builtin_amdgcn_mfma_f32_16x16x32_bf16(al[ks], bh, acc[ni], 0, 0, 0);
        }
    __syncthreads();
    stage_B(WtL_base + (size_t)p * 16384, Bs, t);
    __syncthreads();
#pragma unroll
    for (int ks = 0; ks < 4; ++ks)
#pragma unroll
        for (int ni = 0; ni < 8; ++ni) {
            bf16x8 bl = read_B(Bs, ni * 16 + lr, ks * 4 + lk);
            acc[ni] = __builtin_amdgcn_mfma_f32_16x16x32_bf16(ah[ks], bl, acc[ni], 0, 0, 0);
        }

    const float* bias = bias_cat + p * 128;
    if (p == 0 || p == 3) {
        float* outp = (p == 0) ? qout : skipout;
#pragma unroll
        for (int ni = 0; ni < 8; ++ni) {
            int col = ni * 16 + lr;
            float bc = bias[col];
#pragma unroll
            for (int r = 0; r < 4; ++r) {
                int gr = brow0 + lk * 4 + r;
                if (gr < N) outp[(size_t)gr * 128 + col] = acc[ni][r] + bc;
            }
        }
    } else {
        // packed kv: uint idx = gr*128 + 2*(col>>1) + slot ; pair via shfl_xor(1)
        unsigned int* kvu = (unsigned int*)kvout;
        const int slot = (p == 1) ? 0 : 1;
#pragma unroll
        for (int ni = 0; ni < 8; ++ni) {
            int col = ni * 16 + lr;
            float bc = bias[col];
#pragma unroll
            for (int r = 0; r < 4; ++r) {
                unsigned int s = f2bf(acc[ni][r] + bc);
                unsigned int o = __shfl_xor((int)s, 1);
                int gr = brow0 + lk * 4 + r;
                if (((lr & 1) == 0) && gr < N)
                    kvu[(size_t)gr * 128 + 2 * (col >> 1) + slot] = s | (o << 16);
            }
        }
    }
}

// ---------- out GEMM + residual + fused LayerNorm ----------
__global__ __launch_bounds__(256)
void gemm_out_ln_kernel(const float* __restrict__ A,
                        const unsigned short* __restrict__ BtH_t,
                        const unsigned short* __restrict__ BtL_t,
                        const float* __restrict__ bo,
                        const float* __restrict__ res,
                        const float* __restrict__ gamma,
                        const float* __restrict__ beta,
                        float* __restrict__ out, int N)
{
    __shared__ unsigned short Bs[16384];    // 32KB
    __shared__ float lnS[2][32], lnSq[2][32];
    const int t = threadIdx.x;
    const int lane = t & 63;
    const int w = t >> 6;
    const int lr = lane & 15;
    const int lk = lane >> 4;
    const int ch = w & 1;                   // col half
    const int rg = w >> 1;                  // row group
    const int brow0 = blockIdx.x * 32 + rg * 16;
    const int arow = min(brow0 + lr, N - 1);
    const float* ap = A + (size_t)arow * 128;

    bf16x8 ah[4], al[4];
#pragma unroll
    for (int ks = 0; ks < 4; ++ks) {
        float4 f0 = *reinterpret_cast<const float4*>(ap + ks * 32 + lk * 8);
        float4 f1 = *reinterpret_cast<const float4*>(ap + ks * 32 + lk * 8 + 4);
        split_f8(f0, f1, ah[ks], al[ks]);
    }

    f32x4 acc[4];
#pragma unroll
    for (int ni = 0; ni < 4; ++ni) acc[ni] = (f32x4){0.f, 0.f, 0.f, 0.f};

    stage_B(BtH_t, Bs, t);
    __syncthreads();
#pragma unroll
    for (int ks = 0; ks < 4; ++ks)
#pragma unroll
        for (int ni = 0; ni < 4; ++ni) {
            bf16x8 bh = read_B(Bs, ch * 64 + ni * 16 + lr, ks * 4 + lk);
            acc[ni] = __builtin_amdgcn_mfma_f32_16x16x32_bf16(ah[ks], bh, acc[ni], 0, 0, 0);
            acc[ni] = __builtin_amdgcn_mfma_f32_16x16x32_bf16(al[ks], bh, acc[ni], 0, 0, 0);
        }
    __syncthreads();
    stage_B(BtL_t, Bs, t);
    __syncthreads();
#pragma unroll
    for (int ks = 0; ks < 4; ++ks)
#pragma unroll
        for (int ni = 0; ni < 4; ++ni) {
            bf16x8 bl = read_B(Bs, ch * 64 + ni * 16 + lr, ks * 4 + lk);
            acc[ni] = __builtin_amdgcn_mfma_f32_16x16x32_bf16(ah[ks], bl, acc[ni], 0, 0, 0);
        }

    // add bias + residual
#pragma unroll
    for (int ni = 0; ni < 4; ++ni) {
        int col = ch * 64 + ni * 16 + lr;
        float bc = bo[col];
#pragma unroll
        for (int r = 0; r < 4; ++r) {
            int gr = brow0 + lk * 4 + r;
            float rv = (gr < N) ? res[(size_t)gr * 128 + col] : 0.f;
            acc[ni][r] += bc + rv;
        }
    }
    // per-row partial sums over this wave's 64 cols
    float ps[4], pq[4];
#pragma unroll
    for (int r = 0; r < 4; ++r) {
        float s = 0.f, sq = 0.f;
#pragma unroll
        for (int ni = 0; ni < 4; ++ni) { float v = acc[ni][r]; s += v; sq += v * v; }
#pragma unroll
        for (int mk = 1; mk < 16; mk <<= 1) {
            s  += __shfl_xor(s, mk);
            sq += __shfl_xor(sq, mk);
        }
        ps[r] = s; pq[r] = sq;
    }
    if (lr == 0) {
#pragma unroll
        for (int r = 0; r < 4; ++r) {
            lnS [ch][rg * 16 + lk * 4 + r] = ps[r];
            lnSq[ch][rg * 16 + lk * 4 + r] = pq[r];
        }
    }
    __syncthreads();
#pragma unroll
    for (int r = 0; r < 4; ++r) {
        int rib = rg * 16 + lk * 4 + r;
        float s  = lnS [0][rib] + lnS [1][rib];
        float sq = lnSq[0][rib] + lnSq[1][rib];
        float mean = s * (1.0f / 128.0f);
        float var  = sq * (1.0f / 128.0f) - mean * mean;
        float inv  = rsqrtf(var + 1e-5f);
        int gr = brow0 + lk * 4 + r;
        if (gr < N) {
#pragma unroll
            for (int ni = 0; ni < 4; ++ni) {
                int col = ch * 64 + ni * 16 + lr;
                out[(size_t)gr * 128 + col] =
                    (acc[ni][r] - mean) * inv * gamma[col] + beta[col];
            }
        }
    }
}

// ---------------- exclusive scan (single block, shfl-based) ----------------
__global__ __launch_bounds__(1024)
void scan_kernel(const int* __restrict__ deg, int* __restrict__ offs,
                 int* __restrict__ cursor, int N)
{
    __shared__ int wsum[16];
    __shared__ int chunk_total_s;
    const int t = threadIdx.x;
    const int lane = t & 63, wid = t >> 6;
    int running = 0;
    for (int base = 0; base < N; base += 4096) {
        int v[4];
        int idx = base + t * 4;
#pragma unroll
        for (int j = 0; j < 4; ++j) { int i = idx + j; v[j] = (i < N) ? deg[i] : 0; }
        int ls = v[0] + v[1] + v[2] + v[3];
        int inc = ls;
#pragma unroll
        for (int off = 1; off < 64; off <<= 1) {
            int y = __shfl_up(inc, off);
            if (lane >= off) inc += y;
        }
        if (lane == 63) wsum[wid] = inc;
        __syncthreads();
        if (t < 16) {
            int winc = wsum[t];
            for (int off = 1; off < 16; off <<= 1) {
                int y = __shfl_up(winc, off);
                if (t >= off) winc += y;
            }
            wsum[t] = winc;
            if (t == 15) chunk_total_s = winc;
        }
        __syncthreads();
        int wexcl = (wid == 0) ? 0 : wsum[wid - 1];
        int texcl = running + wexcl + (inc - ls);
        int pre = 0;
#pragma unroll
        for (int j = 0; j < 4; ++j) {
            int i = idx + j;
            if (i < N) { offs[i] = texcl + pre; cursor[i] = texcl + pre; }
            pre += v[j];
        }
        running += chunk_total_s;
        __syncthreads();
    }
    if (t == 0) offs[N] = running;
}

// ---------------- scatter edges into CSR (packed int2 {src, ea}) ----------------
__global__ void scatter_kernel(const int* __restrict__ ei, const float* __restrict__ ea,
                               int* __restrict__ cursor, int2* __restrict__ csr, int E)
{
    int e = blockIdx.x * 256 + threadIdx.x;
    if (e < E) {
        int s = ei[e], d = ei[E + e];
        int pos = atomicAdd(&cursor[d], 1);
        csr[pos] = make_int2(s, __float_as_int(ea[e]));
    }
}

// ---------------- per-node online-softmax attention + aggregation ----------------
// wave per node. Two 32-lane halves each process their own edge stream
// (edges e0+half, e0+half+2, ...). Within a half: 8 heads x 4 lanes x 4 dims.
// Lane h32 (=lane&31) covers dims 4*h32..4*h32+3 (16B of the kv row).
// q.We hoisted per node/head; pv*(v+ea*We) = pv*v + (pv*ea)*We.
__global__ __launch_bounds__(256)
void agg_kernel(const float* __restrict__ qb, const float* __restrict__ sb,
                const unsigned short* __restrict__ kvb,
                const int* __restrict__ offs, const int2* __restrict__ csr,
                const float* __restrict__ We, float* __restrict__ heads_cat, int N)
{
    const int lane = threadIdx.x & 63;
    const int node = blockIdx.x * 4 + (threadIdx.x >> 6);
    if (node >= N) return;
    const int h32 = lane & 31;
    const int half = lane >> 5;

    const float4 q4  = *reinterpret_cast<const float4*>(qb + (size_t)node * 128 + 4 * h32);
    const float4 we4 = *reinterpret_cast<const float4*>(We + 4 * h32);

    // qwe = q . We over this head (reduce over the 4 lanes of the head)
    float qwe = q4.x * we4.x + q4.y * we4.y + q4.z * we4.z + q4.w * we4.w;
    qwe += __shfl_xor(qwe, 1);
    qwe += __shfl_xor(qwe, 2);

    const int e0 = offs[node];
    const int cnt = offs[node + 1] - e0;
    const int myCnt = (cnt > half) ? ((cnt - half + 1) >> 1) : 0;
    const int2* cp = csr + e0 + half;

    float m = -__builtin_huge_valf();
    float s = 0.f, a0 = 0.f, a1 = 0.f, a2 = 0.f, a3 = 0.f;

#define KVG(ec) (*reinterpret_cast<const uint4*>(kvb + (size_t)(ec).x * 256 + 8 * h32))
#define PROC(ec, u) do { \
    float eav_ = __int_as_float((ec).y); \
    float k0_ = __uint_as_float((u).x << 16); \
    float k1_ = __uint_as_float((u).x & 0xffff0000u); \
    float k2_ = __uint_as_float((u).z << 16); \
    float k3_ = __uint_as_float((u).z & 0xffff0000u); \
    float part_ = q4.x * k0_ + q4.y * k1_ + q4.z * k2_ + q4.w * k3_; \
    part_ += __shfl_xor(part_, 1); \
    part_ += __shfl_xor(part_, 2); \
    float alpha_ = (part_ + eav_ * qwe) * 0.25f; \
    float d_ = alpha_ - m; \
    float e_ = __expf(-fabsf(d_)); \
    bool up_ = d_ > 0.f; \
    float pv_ = up_ ? 1.f : e_; \
    float sc_ = up_ ? e_ : 1.f; \
    m = up_ ? alpha_ : m; \
    float t_ = pv_ * eav_; \
    float v0_ = __uint_as_float((u).y << 16); \
    float v1_ = __uint_as_float((u).y & 0xffff0000u); \
    float v2_ = __uint_as_float((u).w << 16); \
    float v3_ = __uint_as_float((u).w & 0xffff0000u); \
    s  = fmaf(s,  sc_, pv_); \
    a0 = fmaf(a0, sc_, fmaf(t_, we4.x, pv_ * v0_)); \
    a1 = fmaf(a1, sc_, fmaf(t_, we4.y, pv_ * v1_)); \
    a2 = fmaf(a2, sc_, fmaf(t_, we4.z, pv_ * v2_)); \
    a3 = fmaf(a3, sc_, fmaf(t_, we4.w, pv_ * v3_)); \
} while (0)

    int2 c0v, c1v, cnv;
    uint4 g0v, g1v;
    if (myCnt > 0) c0v = cp[0];
    if (myCnt > 1) c1v = cp[2];
    if (myCnt > 0) g0v = KVG(c0v);
    if (myCnt > 1) g1v = KVG(c1v);

    for (int j = 0; j < myCnt; ++j) {
        if (j + 2 < myCnt) cnv = cp[2 * j + 4];
        PROC(c0v, g0v);
        c0v = c1v; g0v = g1v; c1v = cnv;
        if (j + 2 < myCnt) g1v = KVG(c1v);
    }

    // merge the two half-states (lane <-> lane^32), guard empty halves via s>0
    float om = __shfl_xor(m, 32);
    float os = __shfl_xor(s, 32);
    float o0 = __shfl_xor(a0, 32);
    float o1 = __shfl_xor(a1, 32);
    float o2 = __shfl_xor(a2, 32);
    float o3 = __shfl_xor(a3, 32);
    float nm = fmaxf(m, om);
    float eS = (s  > 0.f) ? __expf(m  - nm) : 0.f;
    float eO = (os > 0.f) ? __expf(om - nm) : 0.f;
    float st = s * eS + os * eO;
    float r0 = a0 * eS + o0 * eO;
    float r1 = a1 * eS + o1 * eO;
    float r2 = a2 * eS + o2 * eO;
    float r3 = a3 * eS + o3 * eO;

    if (half == 0) {
        float inv = 1.0f / fmaxf(st, 1e-16f);
        const float4 sk = *reinterpret_cast<const float4*>(sb + (size_t)node * 128 + 4 * h32);
        float4 o;
        o.x = r0 * inv + sk.x;
        o.y = r1 * inv + sk.y;
        o.z = r2 * inv + sk.z;
        o.w = r3 * inv + sk.w;
        *reinterpret_cast<float4*>(heads_cat + (size_t)node * 128 + 4 * h32) = o;
    }
#undef KVG
#undef PROC
}

extern "C" void kernel_launch(void* const* d_in, const int* in_sizes, int n_in,
                              void* d_out, int out_size, void* d_ws, size_t ws_size,
                              hipStream_t stream)
{
    const float* x    = (const float*)d_in[0];
    const int*   ei   = (const int*)d_in[1];
    const float* ea   = (const float*)d_in[2];
    const float* Wq   = (const float*)d_in[3];
    const float* bq   = (const float*)d_in[4];
    const float* Wk   = (const float*)d_in[5];
    const float* bk   = (const float*)d_in[6];
    const float* Wv   = (const float*)d_in[7];
    const float* bv   = (const float*)d_in[8];
    const float* We   = (const float*)d_in[9];
    const float* Wsk  = (const float*)d_in[10];
    const float* bsk  = (const float*)d_in[11];
    const float* Wo   = (const float*)d_in[12];
    const float* bo   = (const float*)d_in[13];
    const float* gamma= (const float*)d_in[14];
    const float* beta = (const float*)d_in[15];
    const int N = in_sizes[0] / 128;
    const int E = in_sizes[1] / 2;
    float* out = (float*)d_out;

    char* w = (char*)d_ws;
    float* qarr      = (float*)w; w += (size_t)N * 128 * sizeof(float);
    float* skiparr   = (float*)w; w += (size_t)N * 128 * sizeof(float);
    unsigned short* kv = (unsigned short*)w; w += (size_t)N * 256 * sizeof(unsigned short);
    float* heads_cat = (float*)w; w += (size_t)N * 128 * sizeof(float);
    int*   deg       = (int*)w;   w += ((size_t)N + 16) * sizeof(int);
    int*   offs      = (int*)w;   w += ((size_t)N + 16) * sizeof(int);
    int*   cursor    = (int*)w;   w += ((size_t)N + 16) * sizeof(int);
    int2*  csr       = (int2*)w;  w += (size_t)E * sizeof(int2);
    unsigned short* WtH = (unsigned short*)w; w += (size_t)5 * 16384 * sizeof(unsigned short);
    unsigned short* WtL = (unsigned short*)w; w += (size_t)5 * 16384 * sizeof(unsigned short);
    float* bias_cat  = (float*)w; w += 4 * 128 * sizeof(float);

    hipMemsetAsync(deg, 0, (size_t)N * sizeof(int), stream);

    const int cntBlocks = (E + 255) / 256;
    prep_count_kernel<<<5 + cntBlocks, 256, 0, stream>>>(Wq, Wk, Wv, Wsk, Wo, bq, bk, bv, bsk,
                                                         WtH, WtL, bias_cat, ei, deg, E);

    dim3 gProj((N + 63) / 64, 4);
    gemm_proj_kernel<<<gProj, 256, 0, stream>>>(x, WtH, WtL, bias_cat, qarr, skiparr, kv, N);

    scan_kernel<<<1, 1024, 0, stream>>>(deg, offs, cursor, N);
    scatter_kernel<<<(E + 255) / 256, 256, 0, stream>>>(ei, ea, cursor, csr, E);
    agg_kernel<<<(N + 3) / 4, 256, 0, stream>>>(qarr, skiparr, kv, offs, csr, We, heads_cat, N);

    gemm_out_ln_kernel<<<(N + 31) / 32, 256, 0, stream>>>(heads_cat,
                                                          WtH + (size_t)4 * 16384,
                                                          WtL + (size_t)4 * 16384,
                                                          bo, x, gamma, beta, out, N);
}

// Round 8
// 326.316 us; speedup vs baseline: 1.5242x; 1.0941x over previous
//
#include <hip/hip_runtime.h>
#include <hip/hip_bf16.h>
#include <stdint.h>
#include <math.h>

#define IN_DIM 128
#define H_HEADS 8
#define HD 16

typedef __attribute__((ext_vector_type(8))) short bf16x8;
typedef __attribute__((ext_vector_type(4))) float f32x4;

__device__ __forceinline__ unsigned short f2bf(float f) {
    __hip_bfloat16 h = __float2bfloat16(f);     // RNE
    return reinterpret_cast<unsigned short&>(h);
}
__device__ __forceinline__ float bf2f(unsigned short h) {
    return __uint_as_float(((unsigned int)h) << 16);
}

__device__ __forceinline__ void split_f8(const float4 f0, const float4 f1,
                                         bf16x8& h8, bf16x8& l8) {
    float ff[8] = {f0.x, f0.y, f0.z, f0.w, f1.x, f1.y, f1.z, f1.w};
    union { bf16x8 v; unsigned short u[8]; } H, L;
#pragma unroll
    for (int j = 0; j < 8; ++j) {
        H.u[j] = f2bf(ff[j]);
        L.u[j] = f2bf(ff[j] - bf2f(H.u[j]));
    }
    h8 = H.v; l8 = L.v;
}

// stage one 32KB B matrix ([c][k] 128x128 shorts) into LDS, XOR-swizzled 16B cols
__device__ __forceinline__ void stage_B(const unsigned short* __restrict__ src,
                                        unsigned short* __restrict__ lds, int t)
{
#pragma unroll
    for (int j = 0; j < 8; ++j) {
        int idx16 = t + j * 256;
        int c = idx16 >> 4, kcol = idx16 & 15;
        uint4 v = *reinterpret_cast<const uint4*>(src + (size_t)c * 128 + kcol * 8);
        *reinterpret_cast<uint4*>(lds + c * 128 + ((kcol ^ (c & 15)) * 8)) = v;
    }
}
__device__ __forceinline__ bf16x8 read_B(const unsigned short* __restrict__ lds,
                                         int c, int kcol)
{
    return *reinterpret_cast<const bf16x8*>(lds + c * 128 + ((kcol ^ (c & 15)) * 8));
}

// ---------- prep (5 blocks): W transpose/split + biases; rest: degree histogram ----------
__global__ __launch_bounds__(256)
void prep_count_kernel(const float* __restrict__ Wq, const float* __restrict__ Wk,
                       const float* __restrict__ Wv, const float* __restrict__ Wsk,
                       const float* __restrict__ Wo,
                       const float* __restrict__ bq, const float* __restrict__ bk,
                       const float* __restrict__ bv, const float* __restrict__ bsk,
                       unsigned short* __restrict__ WtH, unsigned short* __restrict__ WtL,
                       float* __restrict__ bias_cat,
                       const int* __restrict__ ei, int* __restrict__ deg, int E)
{
    const int b = blockIdx.x;
    const int t = threadIdx.x;
    if (b >= 5) {
        int e = (b - 5) * 256 + t;
        if (e < E) atomicAdd(&deg[ei[E + e]], 1);
        return;
    }
    const int p = b;
    const float* src = (p == 0) ? Wq : (p == 1) ? Wk : (p == 2) ? Wv : (p == 3) ? Wsk : Wo;
    unsigned short* dh = WtH + (size_t)p * 16384;
    unsigned short* dl = WtL + (size_t)p * 16384;
#pragma unroll
    for (int j = 0; j < 64; ++j) {
        int o = t + j * 256;            // o = c*128 + k
        int c = o >> 7, k = o & 127;
        float v;
        if (p < 4) {
            int h = c >> 4, d = c & 15;
            v = src[(size_t)h * 2048 + (size_t)k * 16 + d];
        } else {
            v = src[(size_t)k * 128 + c];
        }
        unsigned short hi = f2bf(v);
        unsigned short lo = f2bf(v - bf2f(hi));
        dh[o] = hi; dl[o] = lo;
    }
    if (p < 4 && t < 128) {
        const float* bb = (p == 0) ? bq : (p == 1) ? bk : (p == 2) ? bv : bsk;
        bias_cat[p * 128 + t] = bb[t];
    }
}

// ---------- proj GEMM: LDS-staged B (two-pass hi/lo), A direct from global ----------
__global__ __launch_bounds__(256)
void gemm_proj_kernel(const float* __restrict__ A,
                      const unsigned short* __restrict__ WtH_base,
                      const unsigned short* __restrict__ WtL_base,
                      const float* __restrict__ bias_cat,
                      float* __restrict__ qout, float* __restrict__ skipout,
                      unsigned short* __restrict__ kvout, int N)
{
    __shared__ unsigned short Bs[16384];
    const int t = threadIdx.x;
    const int lane = t & 63;
    const int w = t >> 6;
    const int lr = lane & 15;
    const int lk = lane >> 4;
    const int p = blockIdx.y;               // 0=q 1=k 2=v 3=skip
    const int brow0 = blockIdx.x * 64 + w * 16;
    const int arow = min(brow0 + lr, N - 1);
    const float* ap = A + (size_t)arow * 128;

    bf16x8 ah[4], al[4];
#pragma unroll
    for (int ks = 0; ks < 4; ++ks) {
        float4 f0 = *reinterpret_cast<const float4*>(ap + ks * 32 + lk * 8);
        float4 f1 = *reinterpret_cast<const float4*>(ap + ks * 32 + lk * 8 + 4);
        split_f8(f0, f1, ah[ks], al[ks]);
    }

    f32x4 acc[8];
#pragma unroll
    for (int ni = 0; ni < 8; ++ni) acc[ni] = (f32x4){0.f, 0.f, 0.f, 0.f};

    stage_B(WtH_base + (size_t)p * 16384, Bs, t);
    __syncthreads();
#pragma unroll
    for (int ks = 0; ks < 4; ++ks)
#pragma unroll
        for (int ni = 0; ni < 8; ++ni) {
            bf16x8 bh = read_B(Bs, ni * 16 + lr, ks * 4 + lk);
            acc[ni] = __builtin_amdgcn_mfma_f32_16x16x32_bf16(ah[ks], bh, acc[ni], 0, 0, 0);
            acc[ni] = __builtin_amdgcn_mfma_f32_16x16x32_bf16(al[ks], bh, acc[ni], 0, 0, 0);
        }
    __syncthreads();
    stage_B(WtL_base + (size_t)p * 16384, Bs, t);
    __syncthreads();
#pragma unroll
    for (int ks = 0; ks < 4; ++ks)
#pragma unroll
        for (int ni = 0; ni < 8; ++ni) {
            bf16x8 bl = read_B(Bs, ni * 16 + lr, ks * 4 + lk);
            acc[ni] = __builtin_amdgcn_mfma_f32_16x16x32_bf16(ah[ks], bl, acc[ni], 0, 0, 0);
        }

    const float* bias = bias_cat + p * 128;
    if (p == 0 || p == 3) {
        float* outp = (p == 0) ? qout : skipout;
#pragma unroll
        for (int ni = 0; ni < 8; ++ni) {
            int col = ni * 16 + lr;
            float bc = bias[col];
#pragma unroll
            for (int r = 0; r < 4; ++r) {
                int gr = brow0 + lk * 4 + r;
                if (gr < N) outp[(size_t)gr * 128 + col] = acc[ni][r] + bc;
            }
        }
    } else {
        unsigned int* kvu = (unsigned int*)kvout;
        const int slot = (p == 1) ? 0 : 1;
#pragma unroll
        for (int ni = 0; ni < 8; ++ni) {
            int col = ni * 16 + lr;
            float bc = bias[col];
#pragma unroll
            for (int r = 0; r < 4; ++r) {
                unsigned int s = f2bf(acc[ni][r] + bc);
                unsigned int o = __shfl_xor((int)s, 1);
                int gr = brow0 + lk * 4 + r;
                if (((lr & 1) == 0) && gr < N)
                    kvu[(size_t)gr * 128 + 2 * (col >> 1) + slot] = s | (o << 16);
            }
        }
    }
}

// ---------- out GEMM + residual + fused LayerNorm (64-row blocks, in-wave LN) ----------
__global__ __launch_bounds__(256)
void gemm_out_ln_kernel(const float* __restrict__ A,
                        const unsigned short* __restrict__ BtH_t,
                        const unsigned short* __restrict__ BtL_t,
                        const float* __restrict__ bo,
                        const float* __restrict__ res,
                        const float* __restrict__ gamma,
                        const float* __restrict__ beta,
                        float* __restrict__ out, int N)
{
    __shared__ unsigned short Bs[16384];
    const int t = threadIdx.x;
    const int lane = t & 63;
    const int w = t >> 6;
    const int lr = lane & 15;
    const int lk = lane >> 4;
    const int brow0 = blockIdx.x * 64 + w * 16;
    const int arow = min(brow0 + lr, N - 1);
    const float* ap = A + (size_t)arow * 128;

    bf16x8 ah[4], al[4];
#pragma unroll
    for (int ks = 0; ks < 4; ++ks) {
        float4 f0 = *reinterpret_cast<const float4*>(ap + ks * 32 + lk * 8);
        float4 f1 = *reinterpret_cast<const float4*>(ap + ks * 32 + lk * 8 + 4);
        split_f8(f0, f1, ah[ks], al[ks]);
    }

    f32x4 acc[8];
#pragma unroll
    for (int ni = 0; ni < 8; ++ni) acc[ni] = (f32x4){0.f, 0.f, 0.f, 0.f};

    stage_B(BtH_t, Bs, t);
    __syncthreads();
#pragma unroll
    for (int ks = 0; ks < 4; ++ks)
#pragma unroll
        for (int ni = 0; ni < 8; ++ni) {
            bf16x8 bh = read_B(Bs, ni * 16 + lr, ks * 4 + lk);
            acc[ni] = __builtin_amdgcn_mfma_f32_16x16x32_bf16(ah[ks], bh, acc[ni], 0, 0, 0);
            acc[ni] = __builtin_amdgcn_mfma_f32_16x16x32_bf16(al[ks], bh, acc[ni], 0, 0, 0);
        }
    __syncthreads();
    stage_B(BtL_t, Bs, t);
    __syncthreads();
#pragma unroll
    for (int ks = 0; ks < 4; ++ks)
#pragma unroll
        for (int ni = 0; ni < 8; ++ni) {
            bf16x8 bl = read_B(Bs, ni * 16 + lr, ks * 4 + lk);
            acc[ni] = __builtin_amdgcn_mfma_f32_16x16x32_bf16(ah[ks], bl, acc[ni], 0, 0, 0);
        }

    // epilogue: + bo + res; in-wave LN over the 16 lr-lanes; write
#pragma unroll
    for (int ni = 0; ni < 8; ++ni) {
        int col = ni * 16 + lr;
        float bc = bo[col];
#pragma unroll
        for (int r = 0; r < 4; ++r) {
            int gr = brow0 + lk * 4 + r;
            float rv = (gr < N) ? res[(size_t)gr * 128 + col] : 0.f;
            acc[ni][r] += bc + rv;
        }
    }
#pragma unroll
    for (int r = 0; r < 4; ++r) {
        float s = 0.f, sq = 0.f;
#pragma unroll
        for (int ni = 0; ni < 8; ++ni) { float v = acc[ni][r]; s += v; sq += v * v; }
#pragma unroll
        for (int mk = 1; mk < 16; mk <<= 1) {
            s  += __shfl_xor(s, mk);
            sq += __shfl_xor(sq, mk);
        }
        float mean = s * (1.0f / 128.0f);
        float var  = sq * (1.0f / 128.0f) - mean * mean;
        float inv  = rsqrtf(var + 1e-5f);
        int gr = brow0 + lk * 4 + r;
        if (gr < N) {
#pragma unroll
            for (int ni = 0; ni < 8; ++ni) {
                int col = ni * 16 + lr;
                out[(size_t)gr * 128 + col] =
                    (acc[ni][r] - mean) * inv * gamma[col] + beta[col];
            }
        }
    }
}

// ---------------- parallel scan: 3 kernels ----------------
__global__ __launch_bounds__(1024)
void scan_part1(const int* __restrict__ deg, int* __restrict__ offs,
                int* __restrict__ csums, int N)
{
    __shared__ int wsum[16];
    const int t = threadIdx.x;
    const int lane = t & 63, wid = t >> 6;
    const int idx = blockIdx.x * 4096 + t * 4;
    int v[4];
#pragma unroll
    for (int j = 0; j < 4; ++j) { int i = idx + j; v[j] = (i < N) ? deg[i] : 0; }
    int ls = v[0] + v[1] + v[2] + v[3];
    int inc = ls;
#pragma unroll
    for (int off = 1; off < 64; off <<= 1) {
        int y = __shfl_up(inc, off);
        if (lane >= off) inc += y;
    }
    if (lane == 63) wsum[wid] = inc;
    __syncthreads();
    if (t < 16) {
        int winc = wsum[t];
        for (int off = 1; off < 16; off <<= 1) {
            int y = __shfl_up(winc, off);
            if (t >= off) winc += y;
        }
        wsum[t] = winc;
    }
    __syncthreads();
    int wexcl = (wid == 0) ? 0 : wsum[wid - 1];
    int texcl = wexcl + (inc - ls);
    int pre = 0;
#pragma unroll
    for (int j = 0; j < 4; ++j) {
        int i = idx + j;
        if (i < N) offs[i] = texcl + pre;
        pre += v[j];
    }
    if (t == 0) csums[blockIdx.x] = wsum[15];
}

__global__ void scan_part2(int* __restrict__ csums, int nc,
                           int* __restrict__ offs, int N)
{
    const int t = threadIdx.x;          // 64 threads
    int v = (t < nc) ? csums[t] : 0;
    int inc = v;
#pragma unroll
    for (int off = 1; off < 64; off <<= 1) {
        int y = __shfl_up(inc, off);
        if (t >= off) inc += y;
    }
    if (t < nc) csums[t] = inc - v;     // exclusive
    int total = __shfl(inc, nc - 1);
    if (t == 0) offs[N] = total;
}

__global__ __launch_bounds__(1024)
void scan_part3(int* __restrict__ offs, const int* __restrict__ csums,
                int* __restrict__ cursor, int N)
{
    const int coff = csums[blockIdx.x];
    const int idx = blockIdx.x * 4096 + threadIdx.x * 4;
#pragma unroll
    for (int j = 0; j < 4; ++j) {
        int i = idx + j;
        if (i < N) { int val = offs[i] + coff; offs[i] = val; cursor[i] = val; }
    }
}

// ---------------- scatter edges into CSR (packed int2 {src, ea}) ----------------
__global__ void scatter_kernel(const int* __restrict__ ei, const float* __restrict__ ea,
                               int* __restrict__ cursor, int2* __restrict__ csr, int E)
{
    int e = blockIdx.x * 256 + threadIdx.x;
    if (e < E) {
        int s = ei[e], d = ei[E + e];
        int pos = atomicAdd(&cursor[d], 1);
        csr[pos] = make_int2(s, __float_as_int(ea[e]));
    }
}

// ---------------- per-node online-softmax attention + aggregation ----------------
// wave per node, two 32-lane halves with independent edge streams.
// Defer-max (THR=8): common path has no rescale; We-term factored out (sWE).
__global__ __launch_bounds__(256)
void agg_kernel(const float* __restrict__ qb, const float* __restrict__ sb,
                const unsigned short* __restrict__ kvb,
                const int* __restrict__ offs, const int2* __restrict__ csr,
                const float* __restrict__ We, float* __restrict__ heads_cat, int N)
{
    const int lane = threadIdx.x & 63;
    const int node = blockIdx.x * 4 + (threadIdx.x >> 6);
    if (node >= N) return;
    const int h32 = lane & 31;
    const int half = lane >> 5;

    const float4 q4  = *reinterpret_cast<const float4*>(qb + (size_t)node * 128 + 4 * h32);
    const float4 we4 = *reinterpret_cast<const float4*>(We + 4 * h32);

    float qwe = q4.x * we4.x + q4.y * we4.y + q4.z * we4.z + q4.w * we4.w;
    qwe += __shfl_xor(qwe, 1);
    qwe += __shfl_xor(qwe, 2);

    const int e0 = offs[node];
    const int cnt = offs[node + 1] - e0;
    const int myCnt = (cnt > half) ? ((cnt - half + 1) >> 1) : 0;
    const int2* cp = csr + e0 + half;

    float m = -__builtin_huge_valf();
    float s = 0.f, sWE = 0.f, a0 = 0.f, a1 = 0.f, a2 = 0.f, a3 = 0.f;

#define KVG(ec) (*reinterpret_cast<const uint4*>(kvb + (size_t)(ec).x * 256 + 8 * h32))

    int2 c0, c1, c2, c3;
    uint4 g0, g1, g2;
    if (myCnt > 0) c0 = cp[0];
    if (myCnt > 1) c1 = cp[2];
    if (myCnt > 2) c2 = cp[4];
    if (myCnt > 3) c3 = cp[6];
    if (myCnt > 0) g0 = KVG(c0);
    if (myCnt > 1) g1 = KVG(c1);
    if (myCnt > 2) g2 = KVG(c2);

    for (int j = 0; j < myCnt; ++j) {
        const float eav = __int_as_float(c0.y);
        float k0 = __uint_as_float(g0.x << 16);
        float k1 = __uint_as_float(g0.x & 0xffff0000u);
        float k2 = __uint_as_float(g0.z << 16);
        float k3 = __uint_as_float(g0.z & 0xffff0000u);
        float part = q4.x * k0 + q4.y * k1 + q4.z * k2 + q4.w * k3;
        part += __shfl_xor(part, 1);
        part += __shfl_xor(part, 2);
        float alpha = fmaf(eav, qwe, part) * 0.25f;     // 1/sqrt(16)
        float d = alpha - m;
        if (__any(d > 8.f)) {                           // rare (always on 1st iter)
            float nm = fmaxf(m, alpha);
            float sc = __expf(m - nm);                  // m=-inf -> 0
            m = nm; d = alpha - m;
            s *= sc; sWE *= sc; a0 *= sc; a1 *= sc; a2 *= sc; a3 *= sc;
        }
        float pv = __expf(d);                           // <= e^8, bounded
        s += pv;
        sWE = fmaf(pv, eav, sWE);
        float v0 = __uint_as_float(g0.y << 16);
        float v1 = __uint_as_float(g0.y & 0xffff0000u);
        float v2 = __uint_as_float(g0.w << 16);
        float v3 = __uint_as_float(g0.w & 0xffff0000u);
        a0 = fmaf(pv, v0, a0);
        a1 = fmaf(pv, v1, a1);
        a2 = fmaf(pv, v2, a2);
        a3 = fmaf(pv, v3, a3);
        // rotate queues; prefetch csr 4 ahead, gather 3 ahead
        c0 = c1; c1 = c2; c2 = c3;
        g0 = g1; g1 = g2;
        if (j + 4 < myCnt) c3 = cp[2 * j + 8];
        if (j + 3 < myCnt) g2 = KVG(c2);
    }

    // merge half-states (lane <-> lane^32)
    float om  = __shfl_xor(m, 32);
    float os  = __shfl_xor(s, 32);
    float oWE = __shfl_xor(sWE, 32);
    float o0  = __shfl_xor(a0, 32);
    float o1  = __shfl_xor(a1, 32);
    float o2  = __shfl_xor(a2, 32);
    float o3  = __shfl_xor(a3, 32);
    float nm = fmaxf(m, om);
    float eS = (s  > 0.f) ? __expf(m  - nm) : 0.f;
    float eO = (os > 0.f) ? __expf(om - nm) : 0.f;
    float st  = s * eS + os * eO;
    float SWE = sWE * eS + oWE * eO;
    float r0 = a0 * eS + o0 * eO;
    float r1 = a1 * eS + o1 * eO;
    float r2 = a2 * eS + o2 * eO;
    float r3 = a3 * eS + o3 * eO;

    if (half == 0) {
        float inv = 1.0f / fmaxf(st, 1e-16f);
        const float4 sk = *reinterpret_cast<const float4*>(sb + (size_t)node * 128 + 4 * h32);
        float4 o;
        o.x = fmaf(SWE, we4.x, r0) * inv + sk.x;
        o.y = fmaf(SWE, we4.y, r1) * inv + sk.y;
        o.z = fmaf(SWE, we4.z, r2) * inv + sk.z;
        o.w = fmaf(SWE, we4.w, r3) * inv + sk.w;
        *reinterpret_cast<float4*>(heads_cat + (size_t)node * 128 + 4 * h32) = o;
    }
#undef KVG
}

extern "C" void kernel_launch(void* const* d_in, const int* in_sizes, int n_in,
                              void* d_out, int out_size, void* d_ws, size_t ws_size,
                              hipStream_t stream)
{
    const float* x    = (const float*)d_in[0];
    const int*   ei   = (const int*)d_in[1];
    const float* ea   = (const float*)d_in[2];
    const float* Wq   = (const float*)d_in[3];
    const float* bq   = (const float*)d_in[4];
    const float* Wk   = (const float*)d_in[5];
    const float* bk   = (const float*)d_in[6];
    const float* Wv   = (const float*)d_in[7];
    const float* bv   = (const float*)d_in[8];
    const float* We   = (const float*)d_in[9];
    const float* Wsk  = (const float*)d_in[10];
    const float* bsk  = (const float*)d_in[11];
    const float* Wo   = (const float*)d_in[12];
    const float* bo   = (const float*)d_in[13];
    const float* gamma= (const float*)d_in[14];
    const float* beta = (const float*)d_in[15];
    const int N = in_sizes[0] / 128;
    const int E = in_sizes[1] / 2;
    float* out = (float*)d_out;

    char* w = (char*)d_ws;
    float* qarr      = (float*)w; w += (size_t)N * 128 * sizeof(float);
    float* skiparr   = (float*)w; w += (size_t)N * 128 * sizeof(float);
    unsigned short* kv = (unsigned short*)w; w += (size_t)N * 256 * sizeof(unsigned short);
    float* heads_cat = (float*)w; w += (size_t)N * 128 * sizeof(float);
    int*   deg       = (int*)w;   w += ((size_t)N + 16) * sizeof(int);
    int*   offs      = (int*)w;   w += ((size_t)N + 16) * sizeof(int);
    int*   cursor    = (int*)w;   w += ((size_t)N + 16) * sizeof(int);
    int*   csums     = (int*)w;   w += 256 * sizeof(int);
    int2*  csr       = (int2*)w;  w += (size_t)E * sizeof(int2);
    unsigned short* WtH = (unsigned short*)w; w += (size_t)5 * 16384 * sizeof(unsigned short);
    unsigned short* WtL = (unsigned short*)w; w += (size_t)5 * 16384 * sizeof(unsigned short);
    float* bias_cat  = (float*)w; w += 4 * 128 * sizeof(float);

    hipMemsetAsync(deg, 0, (size_t)N * sizeof(int), stream);

    const int cntBlocks = (E + 255) / 256;
    prep_count_kernel<<<5 + cntBlocks, 256, 0, stream>>>(Wq, Wk, Wv, Wsk, Wo, bq, bk, bv, bsk,
                                                         WtH, WtL, bias_cat, ei, deg, E);

    dim3 gProj((N + 63) / 64, 4);
    gemm_proj_kernel<<<gProj, 256, 0, stream>>>(x, WtH, WtL, bias_cat, qarr, skiparr, kv, N);

    const int nChunks = (N + 4095) / 4096;
    scan_part1<<<nChunks, 1024, 0, stream>>>(deg, offs, csums, N);
    scan_part2<<<1, 64, 0, stream>>>(csums, nChunks, offs, N);
    scan_part3<<<nChunks, 1024, 0, stream>>>(offs, csums, cursor, N);

    scatter_kernel<<<(E + 255) / 256, 256, 0, stream>>>(ei, ea, cursor, csr, E);
    agg_kernel<<<(N + 3) / 4, 256, 0, stream>>>(qarr, skiparr, kv, offs, csr, We, heads_cat, N);

    gemm_out_ln_kernel<<<(N + 63) / 64, 256, 0, stream>>>(heads_cat,
                                                          WtH + (size_t)4 * 16384,
                                                          WtL + (size_t)4 * 16384,
                                                          bo, x, gamma, beta, out, N);
}